// Round 9
// baseline (217.976 us; speedup 1.0000x reference)
//
#include <hip/hip_runtime.h>
#include <hip/hip_bf16.h>
#include <cstdint>

// Problem constants
#define BATCH 16
#define HDIM 768
#define WDIM 768
#define HW (HDIM * WDIM)              // 589824
#define NPIX (BATCH * HW)             // 9437184
#define MAX_DET 393216

// fused front-end geometry: 16-row x full-width tiles
#define TILE_R 16
#define NTILES (BATCH * (HDIM / TILE_R))   // 768
#define WORDS_PER_TILE 192                  // 16*768/64
#define LDS_ROWS 20
#define LDS_C 776                           // img col -4..771 (zero-padded)
#define VEC_PER_ROW 194                     // 776/4
#define TOT_VEC (LDS_ROWS * VEC_PER_ROW)    // 3880
#define NTHREADS 384

// ws layout (byte offsets)
#define LOOK_OFF   0u                 // NTILES * 4 = 3072
#define TICKET_OFF 3072u              // 4
#define TOT_OFF    3076u              // 4
#define IDX_OFF    4096u              // MAX_DET * 4

// Output layout (float elements)
#define SIGMA_BASE 0
#define POS_BASE   786432
#define HGT_BASE   1572864
#define GOOD_BASE  2359296

// ---------------------------------------------------------------
// ln(zf), f32: exact exponent split + hw v_log_f32 on mantissa.
// ---------------------------------------------------------------
__device__ __forceinline__ float fast_logf(float zf) {
    int ib = __float_as_int(zf);
    int e = ((ib >> 23) & 255) - 127;
    float m1 = __int_as_float((ib & 0x007fffff) | 0x3f800000);  // [1,2)
    float lg = __builtin_amdgcn_logf(m1);                       // log2(m1)
    return ((float)e + lg) * 0.69314718055994531f;
}

// Reciprocal via HW rcp_f32 seed + 2 f64 Newtons.
__device__ __forceinline__ double fast_rcp(double d) {
    double r = (double)__builtin_amdgcn_rcpf((float)d);
    r = r * (2.0 - d * r);
    r = r * (2.0 - d * r);
    return r;
}

// ---------------------------------------------------------------
// Fused kernel: local-max mask + global ordered compaction.
// Ticket-ordered decoupled lookback (ticket order == start order,
// so spinning on lower tickets cannot deadlock). Lookback slot is a
// single packed u32: status(2b)<<28 | value(<=2^20), so the payload
// travels inside the atomic word (no separate fence needed).
// ---------------------------------------------------------------
__global__ __launch_bounds__(NTHREADS) void fused_kernel(const float* __restrict__ x,
                                                         unsigned* __restrict__ lookback,
                                                         unsigned* __restrict__ ticket,
                                                         int* __restrict__ flat_idx,
                                                         int* __restrict__ total) {
    __shared__ float lds[LDS_ROWS * LDS_C];   // 62080 B
    __shared__ int misc[2];                   // [0]=tile(ticket), [1]=blockoff
    const int tid = threadIdx.x;

    if (tid == 0) misc[0] = (int)atomicAdd(ticket, 1u);
    __syncthreads();
    const int tile = misc[0];
    const int b  = tile / 48;
    const int rt = tile - b * 48;
    const int r0 = rt * TILE_R;
    const float* heat = x + (size_t)b * (2 * HW) + HW;   // channel 1

    // ---- stage thresholded rows r0-2..r0+17, img col-4..771 (OOI=0) ----
    for (int i = tid; i < TOT_VEC; i += NTHREADS) {
        int lr = (unsigned)i / VEC_PER_ROW;
        int q  = i - lr * VEC_PER_ROW;
        int row = r0 - 2 + lr;
        int col = 4 * q - 4;
        float4 v = make_float4(0.f, 0.f, 0.f, 0.f);
        if (row >= 0 && row < HDIM && col >= 0 && col <= WDIM - 4) {
            v = *reinterpret_cast<const float4*>(heat + (size_t)row * WDIM + col);
        }
        float4 t;
        t.x = v.x > 0.5f ? v.x : 0.f;
        t.y = v.y > 0.5f ? v.y : 0.f;
        t.z = v.z > 0.5f ? v.z : 0.f;
        t.w = v.w > 0.5f ? v.w : 0.f;
        *reinterpret_cast<float4*>(&lds[lr * LDS_C + 4 * q]) = t;
    }
    __syncthreads();

    // ---- compute: wave wv = h*3+s -> rows r0+h*8..+7, col strip s*256 ----
    const int wv   = tid >> 6;                // 0..5
    const int lane = tid & 63;
    const int h    = wv / 3;
    const int st   = wv - 3 * h;
    const int lrow0 = h * 8;                  // LDS row of window start

    auto readrow = [&](int ldsrow, float* h5, float* hx, float* tc) {
        const float* p = &lds[ldsrow * LDS_C + st * 256 + 4 * lane];
        float4 a = *reinterpret_cast<const float4*>(p);
        float4 bb = *reinterpret_cast<const float4*>(p + 4);
        float4 cc = *reinterpret_cast<const float4*>(p + 8);
        float t2=a.z,t3=a.w,t4=bb.x,t5=bb.y,t6=bb.z,t7=bb.w,t8=cc.x,t9=cc.y;
        float pp0=fmaxf(t2,t3), pp1=fmaxf(t3,t4), pp2=fmaxf(t4,t5), pp3=fmaxf(t5,t6),
              pp4=fmaxf(t6,t7), pp5=fmaxf(t7,t8), pp6=fmaxf(t8,t9);
        h5[0]=fmaxf(fmaxf(pp0,pp2),t6);  hx[0]=fmaxf(pp0,pp3);  tc[0]=t4;
        h5[1]=fmaxf(fmaxf(pp1,pp3),t7);  hx[1]=fmaxf(pp1,pp4);  tc[1]=t5;
        h5[2]=fmaxf(fmaxf(pp2,pp4),t8);  hx[2]=fmaxf(pp2,pp5);  tc[2]=t6;
        h5[3]=fmaxf(fmaxf(pp3,pp5),t9);  hx[3]=fmaxf(pp3,pp6);  tc[3]=t7;
    };

    float h5r[5][4], hxr[5][4], tcr[5][4];
    #pragma unroll
    for (int j = 0; j < 4; ++j)
        readrow(lrow0 + j, h5r[j], hxr[j], tcr[j]);

    unsigned nibword = 0;                     // 8 nibbles, row k -> shift 4k
    #pragma unroll
    for (int k = 0; k < 8; ++k) {
        readrow(lrow0 + k + 4, h5r[(k+4)%5], hxr[(k+4)%5], tcr[(k+4)%5]);
        unsigned nib = 0;
        #pragma unroll
        for (int c = 0; c < 4; ++c) {
            float dil = fmaxf(fmaxf(h5r[k%5][c], h5r[(k+1)%5][c]),
                        fmaxf(hxr[(k+2)%5][c],
                        fmaxf(h5r[(k+3)%5][c], h5r[(k+4)%5][c])));
            if (tcr[(k+2)%5][c] > dil) nib |= (1u << c);
        }
        nibword |= nib << (4 * k);
    }

    // ---- word assembly in LDS (reuse staging buffer) ----
    __syncthreads();                          // float reads done
    unsigned* lu = (unsigned*)lds;            // [0..383]
    int* su = (int*)lds + 512;                // [512..703]: popcount scan
    lu[tid] = nibword;
    __syncthreads();

    unsigned long long word = 0ull;
    int pc = 0;
    if (tid < WORDS_PER_TILE) {
        const int r   = tid / 12;             // 0..15
        const int c12 = tid - r * 12;
        const int s2  = c12 >> 2;
        const int wi  = c12 & 3;
        const int h2  = r >> 3;
        const int k2  = r & 7;
        const int wv2 = h2 * 3 + s2;
        const int sft = 4 * k2;
        const uint4* p = (const uint4*)&lu[wv2 * 64 + wi * 16];
        uint4 q0 = p[0], q1 = p[1], q2 = p[2], q3 = p[3];
        unsigned lo = 0, hi = 0;
        lo |= ((q0.x >> sft) & 0xFu) << 0;   lo |= ((q0.y >> sft) & 0xFu) << 4;
        lo |= ((q0.z >> sft) & 0xFu) << 8;   lo |= ((q0.w >> sft) & 0xFu) << 12;
        lo |= ((q1.x >> sft) & 0xFu) << 16;  lo |= ((q1.y >> sft) & 0xFu) << 20;
        lo |= ((q1.z >> sft) & 0xFu) << 24;  lo |= ((q1.w >> sft) & 0xFu) << 28;
        hi |= ((q2.x >> sft) & 0xFu) << 0;   hi |= ((q2.y >> sft) & 0xFu) << 4;
        hi |= ((q2.z >> sft) & 0xFu) << 8;   hi |= ((q2.w >> sft) & 0xFu) << 12;
        hi |= ((q3.x >> sft) & 0xFu) << 16;  hi |= ((q3.y >> sft) & 0xFu) << 20;
        hi |= ((q3.z >> sft) & 0xFu) << 24;  hi |= ((q3.w >> sft) & 0xFu) << 28;
        word = (unsigned long long)lo | ((unsigned long long)hi << 32);
        pc = __popcll(word);
        su[tid] = pc;
    }
    __syncthreads();

    // inclusive Hillis-Steele scan over 192 popcounts
    for (int off = 1; off < WORDS_PER_TILE; off <<= 1) {
        int add = 0;
        if (tid < WORDS_PER_TILE && tid >= off) add = su[tid - off];
        __syncthreads();
        if (tid < WORDS_PER_TILE) su[tid] += add;
        __syncthreads();
    }
    const int agg = su[WORDS_PER_TILE - 1];

    // ---- decoupled lookback (thread 0) ----
    if (tid == 0) {
        __hip_atomic_store(&lookback[tile], (1u << 28) | (unsigned)agg,
                           __ATOMIC_RELEASE, __HIP_MEMORY_SCOPE_AGENT);
        unsigned run = 0;
        int p = tile - 1;
        while (p >= 0) {
            unsigned v = __hip_atomic_load(&lookback[p], __ATOMIC_ACQUIRE,
                                           __HIP_MEMORY_SCOPE_AGENT);
            unsigned stx = v >> 28;
            if (stx == 2u) { run += v & 0x0FFFFFFFu; break; }
            if (stx == 1u) { run += v & 0x0FFFFFFFu; --p; }
            // else: not yet published, spin
        }
        __hip_atomic_store(&lookback[tile], (2u << 28) | (unsigned)(run + agg),
                           __ATOMIC_RELEASE, __HIP_MEMORY_SCOPE_AGENT);
        if (tile == NTILES - 1) *total = (int)(run + agg);
        misc[1] = (int)run;
    }
    __syncthreads();

    // ---- scatter set bits in ascending flat order ----
    if (tid < WORDS_PER_TILE) {
        int base = misc[1] + su[tid] - pc;
        int idx0 = (tile * WORDS_PER_TILE + tid) << 6;
        unsigned long long m = word;
        while (m) {
            int j = __builtin_ctzll(m);
            if (base < MAX_DET) flat_idx[base] = idx0 + j;
            ++base;
            m &= m - 1;
        }
    }
}

// ---------------------------------------------------------------
// Fit kernel: batched gather -> f32 moments -> f64 no-pivot GE.
// ---------------------------------------------------------------
__global__ __launch_bounds__(256) void fit_kernel(const float* __restrict__ x,
                                                  const int* __restrict__ flat_idx,
                                                  const int* __restrict__ total,
                                                  float* __restrict__ out) {
    int n = blockIdx.x * 256 + threadIdx.x;   // 0..MAX_DET-1 (grid exact)
    int count = min(*total, MAX_DET);
    float sx = 0.f, sy = 0.f, p0 = 0.f, p1 = 0.f, h0 = 0.f, h1 = 0.f, goodf = 0.f;
    if (n < count) {
        int idx = flat_idx[n];
        int b = idx / HW;
        int rc = idx - b * HW;
        int r = rc / WDIM;
        int c = rc - r * WDIM;
        const float* heat = x + (size_t)b * (2 * HW) + HW;

        // batched gather: all 25 loads issued before any compute
        float zv[25];
        #pragma unroll
        for (int dy = 0; dy < 5; ++dy) {
            int rr = min(max(r + dy - 2, 0), HDIM - 1);
            const float* hp = heat + (size_t)rr * WDIM;
            #pragma unroll
            for (int dx = 0; dx < 5; ++dx) {
                int cc = min(max(c + dx - 2, 0), WDIM - 1);
                zv[dy * 5 + dx] = hp[cc];
            }
        }

        // Row-factorized moments in f32, weight w2 = z^4
        float M00=0,M10=0,M01=0,M20=0,M11=0,M02=0,M30=0,M21=0,M12=0,M03=0;
        float M40=0,M31=0,M22=0,M13=0,M04=0;
        float N0=0,N1=0,N2=0,N3=0,N4=0,N5=0;
        #pragma unroll
        for (int dy = -2; dy <= 2; ++dy) {
            float S0=0,S1=0,S2=0,S3=0,S4=0,T0=0,T1=0,T2=0;
            #pragma unroll
            for (int dx = -2; dx <= 2; ++dx) {
                float zf = fmaxf(zv[(dy + 2) * 5 + dx + 2], 1e-6f);
                float z2 = zf * zf;
                float w2 = z2 * z2;
                float wl = w2 * fast_logf(zf);
                const float X = (float)dx;         // literal after unroll
                S0 += w2; T0 += wl;
                if (dx != 0) {
                    S1 += w2 * X;
                    S2 += w2 * (X * X);
                    S3 += w2 * (X * X * X);
                    S4 += w2 * (X * X * X * X);
                    T1 += wl * X;
                    T2 += wl * (X * X);
                }
            }
            const float Y = (float)dy;             // literal after unroll
            M00 += S0; M10 += S1; M20 += S2; M30 += S3; M40 += S4;
            N0 += T0; N1 += T1; N2 += T2;
            if (dy != 0) {
                float Y2 = Y * Y, Y3 = Y2 * Y, Y4 = Y2 * Y2;
                M01 += S0 * Y;  M11 += S1 * Y;  M21 += S2 * Y;  M31 += S3 * Y;
                M02 += S0 * Y2; M12 += S1 * Y2; M22 += S2 * Y2;
                M03 += S0 * Y3; M13 += S1 * Y3;
                M04 += S0 * Y4;
                N3 += T0 * Y; N4 += T1 * Y; N5 += T0 * Y2;
            }
        }

        // Augmented 6x7 normal equations (f64), basis [1, x, x2, y, xy, y2]
        double A[6][7];
        A[0][0]=M00; A[0][1]=M10; A[0][2]=M20; A[0][3]=M01; A[0][4]=M11; A[0][5]=M02; A[0][6]=N0;
        A[1][0]=M10; A[1][1]=M20; A[1][2]=M30; A[1][3]=M11; A[1][4]=M21; A[1][5]=M12; A[1][6]=N1;
        A[2][0]=M20; A[2][1]=M30; A[2][2]=M40; A[2][3]=M21; A[2][4]=M31; A[2][5]=M22; A[2][6]=N2;
        A[3][0]=M01; A[3][1]=M11; A[3][2]=M21; A[3][3]=M02; A[3][4]=M12; A[3][5]=M03; A[3][6]=N3;
        A[4][0]=M11; A[4][1]=M21; A[4][2]=M31; A[4][3]=M12; A[4][4]=M22; A[4][5]=M13; A[4][6]=N4;
        A[5][0]=M02; A[5][1]=M12; A[5][2]=M22; A[5][3]=M03; A[5][4]=M13; A[5][5]=M04; A[5][6]=N5;

        // Gaussian elimination (no pivot; SPD), fully unrolled -> registers
        #pragma unroll
        for (int i = 0; i < 6; ++i) {
            double inv = fast_rcp(A[i][i]);
            #pragma unroll
            for (int j = i + 1; j < 7; ++j) A[i][j] *= inv;
            #pragma unroll
            for (int ii = i + 1; ii < 6; ++ii) {
                double f = A[ii][i];
                #pragma unroll
                for (int j = i + 1; j < 7; ++j) A[ii][j] -= f * A[i][j];
            }
        }
        double cv[6];
        #pragma unroll
        for (int i = 5; i >= 0; --i) {
            double v = A[i][6];
            #pragma unroll
            for (int j = i + 1; j < 6; ++j) v -= A[i][j] * cv[j];
            cv[i] = v;
        }

        double aqx = cv[2], aqy = cv[5];
        if (aqx < 0.0 && aqy < 0.0) {
            double sx2 = -0.5 * fast_rcp(aqx);
            double sy2 = -0.5 * fast_rcp(aqy);
            sx2 = fmin(sx2, 1e300);
            sy2 = fmin(sy2, 1e300);
            double sigx = sqrt(sx2), sigy = sqrt(sy2);
            double mux = cv[1] * sx2, muy = cv[3] * sy2;
            sx = (float)sigx;
            sy = (float)sigy;
            p0 = (float)((double)r + muy);   // pos[:,0] = r + mu_y
            p1 = (float)((double)c + mux);   // pos[:,1] = c + mu_x
            // height threshold is inf (observed): f32 exp2 path, clamped finite.
            float a0 = (float)((cv[0] + 0.5 * cv[1] * cv[1] * sx2) * 1.4426950408889634);
            float a1 = (float)((cv[4] + 0.5 * cv[3] * cv[3] * sy2) * 1.4426950408889634);
            a0 = fminf(a0, 126.0f);          // exp2(126)=8.5e37: finite in f32
            a1 = fminf(a1, 126.0f);
            h0 = exp2f(a0);
            h1 = exp2f(a1);
            goodf = 1.0f;
        }
    }
    out[SIGMA_BASE + 2 * n]     = sx;
    out[SIGMA_BASE + 2 * n + 1] = sy;
    out[POS_BASE + 2 * n]       = p0;
    out[POS_BASE + 2 * n + 1]   = p1;
    out[HGT_BASE + 2 * n]       = h0;
    out[HGT_BASE + 2 * n + 1]   = h1;
    out[GOOD_BASE + n]          = goodf;
}

extern "C" void kernel_launch(void* const* d_in, const int* in_sizes, int n_in,
                              void* d_out, int out_size, void* d_ws, size_t ws_size,
                              hipStream_t stream) {
    const float* x = (const float*)d_in[0];
    float* out = (float*)d_out;
    char* ws = (char*)d_ws;

    unsigned* lookback = (unsigned*)(ws + LOOK_OFF);
    unsigned* ticket   = (unsigned*)(ws + TICKET_OFF);
    int* total         = (int*)(ws + TOT_OFF);
    int* flatidx       = (int*)(ws + IDX_OFF);

    // zero lookback state + ticket each call (graph-capturable stream op)
    hipMemsetAsync(ws + LOOK_OFF, 0, TICKET_OFF + 4, stream);

    fused_kernel<<<NTILES, NTHREADS, 0, stream>>>(x, lookback, ticket, flatidx, total);
    fit_kernel<<<MAX_DET / 256, 256, 0, stream>>>(x, flatidx, total, out);
}

// Round 10
// 96.040 us; speedup vs baseline: 2.2697x; 2.2697x over previous
//
#include <hip/hip_runtime.h>
#include <hip/hip_bf16.h>
#include <cstdint>

// Problem constants
#define BATCH 16
#define HDIM 768
#define WDIM 768
#define HW (HDIM * WDIM)              // 589824
#define NPIX (BATCH * HW)             // 9437184
#define MAX_DET 393216

// fused front-end geometry: 16-row x full-width tiles
#define TILE_R 16
#define NTILES (BATCH * (HDIM / TILE_R))   // 768
#define WORDS_PER_TILE 192                  // 16*768/64
#define LDS_ROWS 20
#define LDS_C 776                           // img col -4..771 (zero-padded)
#define VEC_PER_ROW 194                     // 776/4
#define TOT_VEC (LDS_ROWS * VEC_PER_ROW)    // 3880
#define NTHREADS 384

// ws layout (byte offsets)
#define LOOK_OFF   0u                 // NTILES * 4 = 3072
#define TICKET_OFF 3072u              // 4
#define TOT_OFF    3076u              // 4
#define IDX_OFF    4096u              // MAX_DET * 4

// Output layout (float elements)
#define SIGMA_BASE 0
#define POS_BASE   786432
#define HGT_BASE   1572864
#define GOOD_BASE  2359296

// ---------------------------------------------------------------
// ln(zf), f32: exact exponent split + hw v_log_f32 on mantissa.
// ---------------------------------------------------------------
__device__ __forceinline__ float fast_logf(float zf) {
    int ib = __float_as_int(zf);
    int e = ((ib >> 23) & 255) - 127;
    float m1 = __int_as_float((ib & 0x007fffff) | 0x3f800000);  // [1,2)
    float lg = __builtin_amdgcn_logf(m1);                       // log2(m1)
    return ((float)e + lg) * 0.69314718055994531f;
}

// Reciprocal via HW rcp_f32 seed + 2 f64 Newtons.
__device__ __forceinline__ double fast_rcp(double d) {
    double r = (double)__builtin_amdgcn_rcpf((float)d);
    r = r * (2.0 - d * r);
    r = r * (2.0 - d * r);
    return r;
}

// ---------------------------------------------------------------
// Fused kernel: local-max mask + global ordered compaction.
// Ticket-ordered decoupled lookback, WAVE-PARALLEL walk: 64 lanes
// probe 64 predecessor tiles per round (serial-walk fix for r9's
// 199us spin). Lookback slot: status(2b)<<28 | value(<=2^20) in one
// atomic word.
// ---------------------------------------------------------------
__global__ __launch_bounds__(NTHREADS) void fused_kernel(const float* __restrict__ x,
                                                         unsigned* __restrict__ lookback,
                                                         unsigned* __restrict__ ticket,
                                                         int* __restrict__ flat_idx,
                                                         int* __restrict__ total) {
    __shared__ float lds[LDS_ROWS * LDS_C];   // 62080 B
    __shared__ int misc[2];                   // [0]=tile(ticket), [1]=blockoff
    const int tid = threadIdx.x;

    if (tid == 0) misc[0] = (int)atomicAdd(ticket, 1u);
    __syncthreads();
    const int tile = misc[0];
    const int b  = tile / 48;
    const int rt = tile - b * 48;
    const int r0 = rt * TILE_R;
    const float* heat = x + (size_t)b * (2 * HW) + HW;   // channel 1

    // ---- stage thresholded rows r0-2..r0+17, img col-4..771 (OOI=0) ----
    for (int i = tid; i < TOT_VEC; i += NTHREADS) {
        int lr = (unsigned)i / VEC_PER_ROW;
        int q  = i - lr * VEC_PER_ROW;
        int row = r0 - 2 + lr;
        int col = 4 * q - 4;
        float4 v = make_float4(0.f, 0.f, 0.f, 0.f);
        if (row >= 0 && row < HDIM && col >= 0 && col <= WDIM - 4) {
            v = *reinterpret_cast<const float4*>(heat + (size_t)row * WDIM + col);
        }
        float4 t;
        t.x = v.x > 0.5f ? v.x : 0.f;
        t.y = v.y > 0.5f ? v.y : 0.f;
        t.z = v.z > 0.5f ? v.z : 0.f;
        t.w = v.w > 0.5f ? v.w : 0.f;
        *reinterpret_cast<float4*>(&lds[lr * LDS_C + 4 * q]) = t;
    }
    __syncthreads();

    // ---- compute: wave wv = h*3+s -> rows r0+h*8..+7, col strip s*256 ----
    const int wv   = tid >> 6;                // 0..5
    const int lane = tid & 63;
    const int h    = wv / 3;
    const int st   = wv - 3 * h;
    const int lrow0 = h * 8;                  // LDS row of window start

    auto readrow = [&](int ldsrow, float* h5, float* hx, float* tc) {
        const float* p = &lds[ldsrow * LDS_C + st * 256 + 4 * lane];
        float4 a = *reinterpret_cast<const float4*>(p);
        float4 bb = *reinterpret_cast<const float4*>(p + 4);
        float4 cc = *reinterpret_cast<const float4*>(p + 8);
        float t2=a.z,t3=a.w,t4=bb.x,t5=bb.y,t6=bb.z,t7=bb.w,t8=cc.x,t9=cc.y;
        float pp0=fmaxf(t2,t3), pp1=fmaxf(t3,t4), pp2=fmaxf(t4,t5), pp3=fmaxf(t5,t6),
              pp4=fmaxf(t6,t7), pp5=fmaxf(t7,t8), pp6=fmaxf(t8,t9);
        h5[0]=fmaxf(fmaxf(pp0,pp2),t6);  hx[0]=fmaxf(pp0,pp3);  tc[0]=t4;
        h5[1]=fmaxf(fmaxf(pp1,pp3),t7);  hx[1]=fmaxf(pp1,pp4);  tc[1]=t5;
        h5[2]=fmaxf(fmaxf(pp2,pp4),t8);  hx[2]=fmaxf(pp2,pp5);  tc[2]=t6;
        h5[3]=fmaxf(fmaxf(pp3,pp5),t9);  hx[3]=fmaxf(pp3,pp6);  tc[3]=t7;
    };

    float h5r[5][4], hxr[5][4], tcr[5][4];
    #pragma unroll
    for (int j = 0; j < 4; ++j)
        readrow(lrow0 + j, h5r[j], hxr[j], tcr[j]);

    unsigned nibword = 0;                     // 8 nibbles, row k -> shift 4k
    #pragma unroll
    for (int k = 0; k < 8; ++k) {
        readrow(lrow0 + k + 4, h5r[(k+4)%5], hxr[(k+4)%5], tcr[(k+4)%5]);
        unsigned nib = 0;
        #pragma unroll
        for (int c = 0; c < 4; ++c) {
            float dil = fmaxf(fmaxf(h5r[k%5][c], h5r[(k+1)%5][c]),
                        fmaxf(hxr[(k+2)%5][c],
                        fmaxf(h5r[(k+3)%5][c], h5r[(k+4)%5][c])));
            if (tcr[(k+2)%5][c] > dil) nib |= (1u << c);
        }
        nibword |= nib << (4 * k);
    }

    // ---- word assembly in LDS (reuse staging buffer) ----
    __syncthreads();                          // float reads done
    unsigned* lu = (unsigned*)lds;            // [0..383]
    int* su = (int*)lds + 512;                // [512..703]: popcount scan
    lu[tid] = nibword;
    __syncthreads();

    unsigned long long word = 0ull;
    int pc = 0;
    if (tid < WORDS_PER_TILE) {
        const int r   = tid / 12;             // 0..15
        const int c12 = tid - r * 12;
        const int s2  = c12 >> 2;
        const int wi  = c12 & 3;
        const int h2  = r >> 3;
        const int k2  = r & 7;
        const int wv2 = h2 * 3 + s2;
        const int sft = 4 * k2;
        const uint4* p = (const uint4*)&lu[wv2 * 64 + wi * 16];
        uint4 q0 = p[0], q1 = p[1], q2 = p[2], q3 = p[3];
        unsigned lo = 0, hi = 0;
        lo |= ((q0.x >> sft) & 0xFu) << 0;   lo |= ((q0.y >> sft) & 0xFu) << 4;
        lo |= ((q0.z >> sft) & 0xFu) << 8;   lo |= ((q0.w >> sft) & 0xFu) << 12;
        lo |= ((q1.x >> sft) & 0xFu) << 16;  lo |= ((q1.y >> sft) & 0xFu) << 20;
        lo |= ((q1.z >> sft) & 0xFu) << 24;  lo |= ((q1.w >> sft) & 0xFu) << 28;
        hi |= ((q2.x >> sft) & 0xFu) << 0;   hi |= ((q2.y >> sft) & 0xFu) << 4;
        hi |= ((q2.z >> sft) & 0xFu) << 8;   hi |= ((q2.w >> sft) & 0xFu) << 12;
        hi |= ((q3.x >> sft) & 0xFu) << 16;  hi |= ((q3.y >> sft) & 0xFu) << 20;
        hi |= ((q3.z >> sft) & 0xFu) << 24;  hi |= ((q3.w >> sft) & 0xFu) << 28;
        word = (unsigned long long)lo | ((unsigned long long)hi << 32);
        pc = __popcll(word);
        su[tid] = pc;
    }
    __syncthreads();

    // inclusive Hillis-Steele scan over 192 popcounts
    for (int off = 1; off < WORDS_PER_TILE; off <<= 1) {
        int add = 0;
        if (tid < WORDS_PER_TILE && tid >= off) add = su[tid - off];
        __syncthreads();
        if (tid < WORDS_PER_TILE) su[tid] += add;
        __syncthreads();
    }
    const int agg = su[WORDS_PER_TILE - 1];

    // ---- decoupled lookback, WAVE-PARALLEL (wave 0: tids 0..63) ----
    if (tid < 64) {
        if (tid == 0)
            __hip_atomic_store(&lookback[tile], (1u << 28) | (unsigned)agg,
                               __ATOMIC_RELEASE, __HIP_MEMORY_SCOPE_AGENT);
        unsigned run = 0;
        int p = tile - 1;
        while (p >= 0) {
            int idx = p - tid;                 // lane tid probes tile idx
            unsigned v = 2u << 28;             // idx<0 sentinel: PREFIX 0
            if (idx >= 0)
                v = __hip_atomic_load(&lookback[idx], __ATOMIC_ACQUIRE,
                                      __HIP_MEMORY_SCOPE_AGENT);
            if (__ballot((v >> 28) == 0u)) {   // someone unpublished: re-poll
                __builtin_amdgcn_s_sleep(1);
                continue;
            }
            unsigned long long pm = __ballot((v >> 28) == 2u);
            int lim = pm ? __builtin_ctzll(pm) : 63;   // nearest PREFIX lane
            unsigned contrib = ((int)tid <= lim) ? (v & 0x0FFFFFFFu) : 0u;
            #pragma unroll
            for (int o = 32; o > 0; o >>= 1) contrib += __shfl_xor(contrib, o);
            run += contrib;
            if (pm) break;
            p -= 64;
        }
        if (tid == 0) {
            __hip_atomic_store(&lookback[tile], (2u << 28) | (unsigned)(run + agg),
                               __ATOMIC_RELEASE, __HIP_MEMORY_SCOPE_AGENT);
            if (tile == NTILES - 1) *total = (int)(run + agg);
            misc[1] = (int)run;
        }
    }
    __syncthreads();

    // ---- scatter set bits in ascending flat order ----
    if (tid < WORDS_PER_TILE) {
        int base = misc[1] + su[tid] - pc;
        int idx0 = (tile * WORDS_PER_TILE + tid) << 6;
        unsigned long long m = word;
        while (m) {
            int j = __builtin_ctzll(m);
            if (base < MAX_DET) flat_idx[base] = idx0 + j;
            ++base;
            m &= m - 1;
        }
    }
}

// ---------------------------------------------------------------
// Fit kernel: batched gather -> f32 moments -> f64 no-pivot GE.
// ---------------------------------------------------------------
__global__ __launch_bounds__(256) void fit_kernel(const float* __restrict__ x,
                                                  const int* __restrict__ flat_idx,
                                                  const int* __restrict__ total,
                                                  float* __restrict__ out) {
    int n = blockIdx.x * 256 + threadIdx.x;   // 0..MAX_DET-1 (grid exact)
    int count = min(*total, MAX_DET);
    float sx = 0.f, sy = 0.f, p0 = 0.f, p1 = 0.f, h0 = 0.f, h1 = 0.f, goodf = 0.f;
    if (n < count) {
        int idx = flat_idx[n];
        int b = idx / HW;
        int rc = idx - b * HW;
        int r = rc / WDIM;
        int c = rc - r * WDIM;
        const float* heat = x + (size_t)b * (2 * HW) + HW;

        // batched gather: all 25 loads issued before any compute
        float zv[25];
        #pragma unroll
        for (int dy = 0; dy < 5; ++dy) {
            int rr = min(max(r + dy - 2, 0), HDIM - 1);
            const float* hp = heat + (size_t)rr * WDIM;
            #pragma unroll
            for (int dx = 0; dx < 5; ++dx) {
                int cc = min(max(c + dx - 2, 0), WDIM - 1);
                zv[dy * 5 + dx] = hp[cc];
            }
        }

        // Row-factorized moments in f32, weight w2 = z^4
        float M00=0,M10=0,M01=0,M20=0,M11=0,M02=0,M30=0,M21=0,M12=0,M03=0;
        float M40=0,M31=0,M22=0,M13=0,M04=0;
        float N0=0,N1=0,N2=0,N3=0,N4=0,N5=0;
        #pragma unroll
        for (int dy = -2; dy <= 2; ++dy) {
            float S0=0,S1=0,S2=0,S3=0,S4=0,T0=0,T1=0,T2=0;
            #pragma unroll
            for (int dx = -2; dx <= 2; ++dx) {
                float zf = fmaxf(zv[(dy + 2) * 5 + dx + 2], 1e-6f);
                float z2 = zf * zf;
                float w2 = z2 * z2;
                float wl = w2 * fast_logf(zf);
                const float X = (float)dx;         // literal after unroll
                S0 += w2; T0 += wl;
                if (dx != 0) {
                    S1 += w2 * X;
                    S2 += w2 * (X * X);
                    S3 += w2 * (X * X * X);
                    S4 += w2 * (X * X * X * X);
                    T1 += wl * X;
                    T2 += wl * (X * X);
                }
            }
            const float Y = (float)dy;             // literal after unroll
            M00 += S0; M10 += S1; M20 += S2; M30 += S3; M40 += S4;
            N0 += T0; N1 += T1; N2 += T2;
            if (dy != 0) {
                float Y2 = Y * Y, Y3 = Y2 * Y, Y4 = Y2 * Y2;
                M01 += S0 * Y;  M11 += S1 * Y;  M21 += S2 * Y;  M31 += S3 * Y;
                M02 += S0 * Y2; M12 += S1 * Y2; M22 += S2 * Y2;
                M03 += S0 * Y3; M13 += S1 * Y3;
                M04 += S0 * Y4;
                N3 += T0 * Y; N4 += T1 * Y; N5 += T0 * Y2;
            }
        }

        // Augmented 6x7 normal equations (f64), basis [1, x, x2, y, xy, y2]
        double A[6][7];
        A[0][0]=M00; A[0][1]=M10; A[0][2]=M20; A[0][3]=M01; A[0][4]=M11; A[0][5]=M02; A[0][6]=N0;
        A[1][0]=M10; A[1][1]=M20; A[1][2]=M30; A[1][3]=M11; A[1][4]=M21; A[1][5]=M12; A[1][6]=N1;
        A[2][0]=M20; A[2][1]=M30; A[2][2]=M40; A[2][3]=M21; A[2][4]=M31; A[2][5]=M22; A[2][6]=N2;
        A[3][0]=M01; A[3][1]=M11; A[3][2]=M21; A[3][3]=M02; A[3][4]=M12; A[3][5]=M03; A[3][6]=N3;
        A[4][0]=M11; A[4][1]=M21; A[4][2]=M31; A[4][3]=M12; A[4][4]=M22; A[4][5]=M13; A[4][6]=N4;
        A[5][0]=M02; A[5][1]=M12; A[5][2]=M22; A[5][3]=M03; A[5][4]=M13; A[5][5]=M04; A[5][6]=N5;

        // Gaussian elimination (no pivot; SPD), fully unrolled -> registers
        #pragma unroll
        for (int i = 0; i < 6; ++i) {
            double inv = fast_rcp(A[i][i]);
            #pragma unroll
            for (int j = i + 1; j < 7; ++j) A[i][j] *= inv;
            #pragma unroll
            for (int ii = i + 1; ii < 6; ++ii) {
                double f = A[ii][i];
                #pragma unroll
                for (int j = i + 1; j < 7; ++j) A[ii][j] -= f * A[i][j];
            }
        }
        double cv[6];
        #pragma unroll
        for (int i = 5; i >= 0; --i) {
            double v = A[i][6];
            #pragma unroll
            for (int j = i + 1; j < 6; ++j) v -= A[i][j] * cv[j];
            cv[i] = v;
        }

        double aqx = cv[2], aqy = cv[5];
        if (aqx < 0.0 && aqy < 0.0) {
            double sx2 = -0.5 * fast_rcp(aqx);
            double sy2 = -0.5 * fast_rcp(aqy);
            sx2 = fmin(sx2, 1e300);
            sy2 = fmin(sy2, 1e300);
            double sigx = sqrt(sx2), sigy = sqrt(sy2);
            double mux = cv[1] * sx2, muy = cv[3] * sy2;
            sx = (float)sigx;
            sy = (float)sigy;
            p0 = (float)((double)r + muy);   // pos[:,0] = r + mu_y
            p1 = (float)((double)c + mux);   // pos[:,1] = c + mu_x
            // height threshold is inf (observed): f32 exp2 path, clamped finite.
            float a0 = (float)((cv[0] + 0.5 * cv[1] * cv[1] * sx2) * 1.4426950408889634);
            float a1 = (float)((cv[4] + 0.5 * cv[3] * cv[3] * sy2) * 1.4426950408889634);
            a0 = fminf(a0, 126.0f);          // exp2(126)=8.5e37: finite in f32
            a1 = fminf(a1, 126.0f);
            h0 = exp2f(a0);
            h1 = exp2f(a1);
            goodf = 1.0f;
        }
    }
    out[SIGMA_BASE + 2 * n]     = sx;
    out[SIGMA_BASE + 2 * n + 1] = sy;
    out[POS_BASE + 2 * n]       = p0;
    out[POS_BASE + 2 * n + 1]   = p1;
    out[HGT_BASE + 2 * n]       = h0;
    out[HGT_BASE + 2 * n + 1]   = h1;
    out[GOOD_BASE + n]          = goodf;
}

extern "C" void kernel_launch(void* const* d_in, const int* in_sizes, int n_in,
                              void* d_out, int out_size, void* d_ws, size_t ws_size,
                              hipStream_t stream) {
    const float* x = (const float*)d_in[0];
    float* out = (float*)d_out;
    char* ws = (char*)d_ws;

    unsigned* lookback = (unsigned*)(ws + LOOK_OFF);
    unsigned* ticket   = (unsigned*)(ws + TICKET_OFF);
    int* total         = (int*)(ws + TOT_OFF);
    int* flatidx       = (int*)(ws + IDX_OFF);

    // zero lookback state + ticket each call (graph-capturable stream op)
    hipMemsetAsync(ws + LOOK_OFF, 0, TICKET_OFF + 4, stream);

    fused_kernel<<<NTILES, NTHREADS, 0, stream>>>(x, lookback, ticket, flatidx, total);
    fit_kernel<<<MAX_DET / 256, 256, 0, stream>>>(x, flatidx, total, out);
}

// Round 11
// 51.525 us; speedup vs baseline: 4.2305x; 1.8639x over previous
//
#include <hip/hip_runtime.h>
#include <hip/hip_bf16.h>
#include <cstdint>

// Problem constants
#define BATCH 16
#define HDIM 768
#define WDIM 768
#define HW (HDIM * WDIM)              // 589824
#define NPIX (BATCH * HW)             // 9437184
#define MAX_DET 393216

// front-end geometry: 16-row x full-width tiles (contiguous in flat order)
#define TILE_R 16
#define NTILES (BATCH * (HDIM / TILE_R))   // 768
#define WORDS_PER_TILE 192                  // 16*768/64
#define LDS_ROWS 20
#define LDS_C 776                           // img col -4..771 (zero-padded)
#define VEC_PER_ROW 194                     // 776/4
#define TOT_VEC (LDS_ROWS * VEC_PER_ROW)    // 3880
#define NTHREADS 384

// ws layout (byte offsets)
#define WORD_OFF 0u                   // NWORDS * 8 = 1179648
#define CNT_OFF  1179648u             // NTILES * 4 = 3072
#define TOT_OFF  1182720u             // 4
#define IDX_OFF  1183744u             // MAX_DET * 4

// Output layout (float elements)
#define SIGMA_BASE 0
#define POS_BASE   786432
#define HGT_BASE   1572864
#define GOOD_BASE  2359296

// ---------------------------------------------------------------
// ln(zf), f32: exact exponent split + hw v_log_f32 on mantissa.
// ---------------------------------------------------------------
__device__ __forceinline__ float fast_logf(float zf) {
    int ib = __float_as_int(zf);
    int e = ((ib >> 23) & 255) - 127;
    float m1 = __int_as_float((ib & 0x007fffff) | 0x3f800000);  // [1,2)
    float lg = __builtin_amdgcn_logf(m1);                       // log2(m1)
    return ((float)e + lg) * 0.69314718055994531f;
}

// Reciprocal via HW rcp_f32 seed + 2 f64 Newtons.
__device__ __forceinline__ double fast_rcp(double d) {
    double r = (double)__builtin_amdgcn_rcpf((float)d);
    r = r * (2.0 - d * r);
    r = r * (2.0 - d * r);
    return r;
}

// ---------------------------------------------------------------
// Kernel 1: local-max mask words + per-tile popcount.
// ---------------------------------------------------------------
__global__ __launch_bounds__(NTHREADS) void maskcount_kernel(const float* __restrict__ x,
                                                             unsigned long long* __restrict__ words,
                                                             int* __restrict__ counts) {
    __shared__ float lds[LDS_ROWS * LDS_C];   // 62080 B
    const int tid  = threadIdx.x;
    const int tile = blockIdx.x;
    const int b  = tile / 48;
    const int rt = tile - b * 48;
    const int r0 = rt * TILE_R;
    const float* heat = x + (size_t)b * (2 * HW) + HW;   // channel 1

    // ---- stage thresholded rows r0-2..r0+17, img col-4..771 (OOI=0) ----
    for (int i = tid; i < TOT_VEC; i += NTHREADS) {
        int lr = (unsigned)i / VEC_PER_ROW;
        int q  = i - lr * VEC_PER_ROW;
        int row = r0 - 2 + lr;
        int col = 4 * q - 4;
        float4 v = make_float4(0.f, 0.f, 0.f, 0.f);
        if (row >= 0 && row < HDIM && col >= 0 && col <= WDIM - 4) {
            v = *reinterpret_cast<const float4*>(heat + (size_t)row * WDIM + col);
        }
        float4 t;
        t.x = v.x > 0.5f ? v.x : 0.f;
        t.y = v.y > 0.5f ? v.y : 0.f;
        t.z = v.z > 0.5f ? v.z : 0.f;
        t.w = v.w > 0.5f ? v.w : 0.f;
        *reinterpret_cast<float4*>(&lds[lr * LDS_C + 4 * q]) = t;
    }
    __syncthreads();

    // ---- compute: wave wv = h*3+s -> rows r0+h*8..+7, col strip s*256 ----
    const int wv   = tid >> 6;                // 0..5
    const int lane = tid & 63;
    const int h    = wv / 3;
    const int st   = wv - 3 * h;
    const int lrow0 = h * 8;                  // LDS row of window start

    auto readrow = [&](int ldsrow, float* h5, float* hx, float* tc) {
        const float* p = &lds[ldsrow * LDS_C + st * 256 + 4 * lane];
        float4 a = *reinterpret_cast<const float4*>(p);
        float4 bb = *reinterpret_cast<const float4*>(p + 4);
        float4 cc = *reinterpret_cast<const float4*>(p + 8);
        float t2=a.z,t3=a.w,t4=bb.x,t5=bb.y,t6=bb.z,t7=bb.w,t8=cc.x,t9=cc.y;
        float pp0=fmaxf(t2,t3), pp1=fmaxf(t3,t4), pp2=fmaxf(t4,t5), pp3=fmaxf(t5,t6),
              pp4=fmaxf(t6,t7), pp5=fmaxf(t7,t8), pp6=fmaxf(t8,t9);
        h5[0]=fmaxf(fmaxf(pp0,pp2),t6);  hx[0]=fmaxf(pp0,pp3);  tc[0]=t4;
        h5[1]=fmaxf(fmaxf(pp1,pp3),t7);  hx[1]=fmaxf(pp1,pp4);  tc[1]=t5;
        h5[2]=fmaxf(fmaxf(pp2,pp4),t8);  hx[2]=fmaxf(pp2,pp5);  tc[2]=t6;
        h5[3]=fmaxf(fmaxf(pp3,pp5),t9);  hx[3]=fmaxf(pp3,pp6);  tc[3]=t7;
    };

    float h5r[5][4], hxr[5][4], tcr[5][4];
    #pragma unroll
    for (int j = 0; j < 4; ++j)
        readrow(lrow0 + j, h5r[j], hxr[j], tcr[j]);

    unsigned nibword = 0;                     // 8 nibbles, row k -> shift 4k
    #pragma unroll
    for (int k = 0; k < 8; ++k) {
        readrow(lrow0 + k + 4, h5r[(k+4)%5], hxr[(k+4)%5], tcr[(k+4)%5]);
        unsigned nib = 0;
        #pragma unroll
        for (int c = 0; c < 4; ++c) {
            float dil = fmaxf(fmaxf(h5r[k%5][c], h5r[(k+1)%5][c]),
                        fmaxf(hxr[(k+2)%5][c],
                        fmaxf(h5r[(k+3)%5][c], h5r[(k+4)%5][c])));
            if (tcr[(k+2)%5][c] > dil) nib |= (1u << c);
        }
        nibword |= nib << (4 * k);
    }

    // ---- word assembly in LDS (reuse staging buffer) ----
    __syncthreads();                          // float reads done
    unsigned* lu = (unsigned*)lds;            // [0..383]
    int* su = (int*)lds + 512;                // [512..767]: popcount reduce
    lu[tid] = nibword;
    __syncthreads();

    int pc = 0;
    if (tid < WORDS_PER_TILE) {
        const int r   = tid / 12;             // 0..15
        const int c12 = tid - r * 12;
        const int s2  = c12 >> 2;
        const int wi  = c12 & 3;
        const int h2  = r >> 3;
        const int k2  = r & 7;
        const int wv2 = h2 * 3 + s2;
        const int sft = 4 * k2;
        const uint4* p = (const uint4*)&lu[wv2 * 64 + wi * 16];
        uint4 q0 = p[0], q1 = p[1], q2 = p[2], q3 = p[3];
        unsigned lo = 0, hi = 0;
        lo |= ((q0.x >> sft) & 0xFu) << 0;   lo |= ((q0.y >> sft) & 0xFu) << 4;
        lo |= ((q0.z >> sft) & 0xFu) << 8;   lo |= ((q0.w >> sft) & 0xFu) << 12;
        lo |= ((q1.x >> sft) & 0xFu) << 16;  lo |= ((q1.y >> sft) & 0xFu) << 20;
        lo |= ((q1.z >> sft) & 0xFu) << 24;  lo |= ((q1.w >> sft) & 0xFu) << 28;
        hi |= ((q2.x >> sft) & 0xFu) << 0;   hi |= ((q2.y >> sft) & 0xFu) << 4;
        hi |= ((q2.z >> sft) & 0xFu) << 8;   hi |= ((q2.w >> sft) & 0xFu) << 12;
        hi |= ((q3.x >> sft) & 0xFu) << 16;  hi |= ((q3.y >> sft) & 0xFu) << 20;
        hi |= ((q3.z >> sft) & 0xFu) << 24;  hi |= ((q3.w >> sft) & 0xFu) << 28;
        unsigned long long word = (unsigned long long)lo |
                                  ((unsigned long long)hi << 32);
        words[tile * WORDS_PER_TILE + tid] = word;
        pc = __popcll(word);
    }
    // per-tile popcount reduce (pad to 256)
    if (tid < 256) su[tid] = (tid < WORDS_PER_TILE) ? pc : 0;
    __syncthreads();
    for (int off = 128; off > 0; off >>= 1) {
        if (tid < off) su[tid] += su[tid + off];
        __syncthreads();
    }
    if (tid == 0) counts[tile] = su[0];
}

// ---------------------------------------------------------------
// Kernel 2: ordered scatter. Tile words are contiguous in flat
// order, so blockoff = sum(counts[0..tile)).
// ---------------------------------------------------------------
__global__ __launch_bounds__(192) void scatter_kernel(const unsigned long long* __restrict__ words,
                                                      const int* __restrict__ counts,
                                                      int* __restrict__ flat_idx,
                                                      int* __restrict__ total) {
    __shared__ int s[256];
    __shared__ int s2[WORDS_PER_TILE];
    __shared__ int blockoff;
    const int t = threadIdx.x;                // 0..191
    const int tile = blockIdx.x;

    // exclusive prefix over tiles [0, tile)
    int acc = 0;
    for (int i = t; i < tile; i += 192) acc += counts[i];
    s[t] = acc;
    if (t < 64) s[192 + t] = 0;
    __syncthreads();
    for (int off = 128; off > 0; off >>= 1) {
        if (t < off) s[t] += s[t + off];
        __syncthreads();
    }
    if (t == 0) blockoff = s[0];
    __syncthreads();

    // load word, in-block inclusive scan of popcounts
    unsigned long long m = words[tile * WORDS_PER_TILE + t];
    int pc = __popcll(m);
    s2[t] = pc;
    __syncthreads();
    for (int off = 1; off < WORDS_PER_TILE; off <<= 1) {
        int add = (t >= off) ? s2[t - off] : 0;
        __syncthreads();
        s2[t] += add;
        __syncthreads();
    }
    if (tile == NTILES - 1 && t == WORDS_PER_TILE - 1)
        *total = blockoff + s2[t];

    int base = blockoff + s2[t] - pc;
    int idx0 = (tile * WORDS_PER_TILE + t) << 6;
    while (m) {
        int j = __builtin_ctzll(m);
        if (base < MAX_DET) flat_idx[base] = idx0 + j;
        ++base;
        m &= m - 1;
    }
}

// ---------------------------------------------------------------
// Kernel 3: fit — batched gather -> f32 moments -> f64 no-pivot GE.
// ---------------------------------------------------------------
__global__ __launch_bounds__(256) void fit_kernel(const float* __restrict__ x,
                                                  const int* __restrict__ flat_idx,
                                                  const int* __restrict__ total,
                                                  float* __restrict__ out) {
    int n = blockIdx.x * 256 + threadIdx.x;   // 0..MAX_DET-1 (grid exact)
    int count = min(*total, MAX_DET);
    float sx = 0.f, sy = 0.f, p0 = 0.f, p1 = 0.f, h0 = 0.f, h1 = 0.f, goodf = 0.f;
    if (n < count) {
        int idx = flat_idx[n];
        int b = idx / HW;
        int rc = idx - b * HW;
        int r = rc / WDIM;
        int c = rc - r * WDIM;
        const float* heat = x + (size_t)b * (2 * HW) + HW;

        // batched gather: all 25 loads issued before any compute
        float zv[25];
        #pragma unroll
        for (int dy = 0; dy < 5; ++dy) {
            int rr = min(max(r + dy - 2, 0), HDIM - 1);
            const float* hp = heat + (size_t)rr * WDIM;
            #pragma unroll
            for (int dx = 0; dx < 5; ++dx) {
                int cc = min(max(c + dx - 2, 0), WDIM - 1);
                zv[dy * 5 + dx] = hp[cc];
            }
        }

        // Row-factorized moments in f32, weight w2 = z^4
        float M00=0,M10=0,M01=0,M20=0,M11=0,M02=0,M30=0,M21=0,M12=0,M03=0;
        float M40=0,M31=0,M22=0,M13=0,M04=0;
        float N0=0,N1=0,N2=0,N3=0,N4=0,N5=0;
        #pragma unroll
        for (int dy = -2; dy <= 2; ++dy) {
            float S0=0,S1=0,S2=0,S3=0,S4=0,T0=0,T1=0,T2=0;
            #pragma unroll
            for (int dx = -2; dx <= 2; ++dx) {
                float zf = fmaxf(zv[(dy + 2) * 5 + dx + 2], 1e-6f);
                float z2 = zf * zf;
                float w2 = z2 * z2;
                float wl = w2 * fast_logf(zf);
                const float X = (float)dx;         // literal after unroll
                S0 += w2; T0 += wl;
                if (dx != 0) {
                    S1 += w2 * X;
                    S2 += w2 * (X * X);
                    S3 += w2 * (X * X * X);
                    S4 += w2 * (X * X * X * X);
                    T1 += wl * X;
                    T2 += wl * (X * X);
                }
            }
            const float Y = (float)dy;             // literal after unroll
            M00 += S0; M10 += S1; M20 += S2; M30 += S3; M40 += S4;
            N0 += T0; N1 += T1; N2 += T2;
            if (dy != 0) {
                float Y2 = Y * Y, Y3 = Y2 * Y, Y4 = Y2 * Y2;
                M01 += S0 * Y;  M11 += S1 * Y;  M21 += S2 * Y;  M31 += S3 * Y;
                M02 += S0 * Y2; M12 += S1 * Y2; M22 += S2 * Y2;
                M03 += S0 * Y3; M13 += S1 * Y3;
                M04 += S0 * Y4;
                N3 += T0 * Y; N4 += T1 * Y; N5 += T0 * Y2;
            }
        }

        // Augmented 6x7 normal equations (f64), basis [1, x, x2, y, xy, y2]
        double A[6][7];
        A[0][0]=M00; A[0][1]=M10; A[0][2]=M20; A[0][3]=M01; A[0][4]=M11; A[0][5]=M02; A[0][6]=N0;
        A[1][0]=M10; A[1][1]=M20; A[1][2]=M30; A[1][3]=M11; A[1][4]=M21; A[1][5]=M12; A[1][6]=N1;
        A[2][0]=M20; A[2][1]=M30; A[2][2]=M40; A[2][3]=M21; A[2][4]=M31; A[2][5]=M22; A[2][6]=N2;
        A[3][0]=M01; A[3][1]=M11; A[3][2]=M21; A[3][3]=M02; A[3][4]=M12; A[3][5]=M03; A[3][6]=N3;
        A[4][0]=M11; A[4][1]=M21; A[4][2]=M31; A[4][3]=M12; A[4][4]=M22; A[4][5]=M13; A[4][6]=N4;
        A[5][0]=M02; A[5][1]=M12; A[5][2]=M22; A[5][3]=M03; A[5][4]=M13; A[5][5]=M04; A[5][6]=N5;

        // Gaussian elimination (no pivot; SPD), fully unrolled -> registers
        #pragma unroll
        for (int i = 0; i < 6; ++i) {
            double inv = fast_rcp(A[i][i]);
            #pragma unroll
            for (int j = i + 1; j < 7; ++j) A[i][j] *= inv;
            #pragma unroll
            for (int ii = i + 1; ii < 6; ++ii) {
                double f = A[ii][i];
                #pragma unroll
                for (int j = i + 1; j < 7; ++j) A[ii][j] -= f * A[i][j];
            }
        }
        double cv[6];
        #pragma unroll
        for (int i = 5; i >= 0; --i) {
            double v = A[i][6];
            #pragma unroll
            for (int j = i + 1; j < 6; ++j) v -= A[i][j] * cv[j];
            cv[i] = v;
        }

        double aqx = cv[2], aqy = cv[5];
        if (aqx < 0.0 && aqy < 0.0) {
            double sx2 = -0.5 * fast_rcp(aqx);
            double sy2 = -0.5 * fast_rcp(aqy);
            sx2 = fmin(sx2, 1e300);
            sy2 = fmin(sy2, 1e300);
            double sigx = sqrt(sx2), sigy = sqrt(sy2);
            double mux = cv[1] * sx2, muy = cv[3] * sy2;
            sx = (float)sigx;
            sy = (float)sigy;
            p0 = (float)((double)r + muy);   // pos[:,0] = r + mu_y
            p1 = (float)((double)c + mux);   // pos[:,1] = c + mu_x
            // height threshold is inf (observed): f32 exp2 path, clamped finite.
            float a0 = (float)((cv[0] + 0.5 * cv[1] * cv[1] * sx2) * 1.4426950408889634);
            float a1 = (float)((cv[4] + 0.5 * cv[3] * cv[3] * sy2) * 1.4426950408889634);
            a0 = fminf(a0, 126.0f);          // exp2(126)=8.5e37: finite in f32
            a1 = fminf(a1, 126.0f);
            h0 = exp2f(a0);
            h1 = exp2f(a1);
            goodf = 1.0f;
        }
    }
    out[SIGMA_BASE + 2 * n]     = sx;
    out[SIGMA_BASE + 2 * n + 1] = sy;
    out[POS_BASE + 2 * n]       = p0;
    out[POS_BASE + 2 * n + 1]   = p1;
    out[HGT_BASE + 2 * n]       = h0;
    out[HGT_BASE + 2 * n + 1]   = h1;
    out[GOOD_BASE + n]          = goodf;
}

extern "C" void kernel_launch(void* const* d_in, const int* in_sizes, int n_in,
                              void* d_out, int out_size, void* d_ws, size_t ws_size,
                              hipStream_t stream) {
    const float* x = (const float*)d_in[0];
    float* out = (float*)d_out;
    char* ws = (char*)d_ws;

    unsigned long long* words = (unsigned long long*)(ws + WORD_OFF);
    int* counts  = (int*)(ws + CNT_OFF);
    int* total   = (int*)(ws + TOT_OFF);
    int* flatidx = (int*)(ws + IDX_OFF);

    maskcount_kernel<<<NTILES, NTHREADS, 0, stream>>>(x, words, counts);
    scatter_kernel<<<NTILES, 192, 0, stream>>>(words, counts, flatidx, total);
    fit_kernel<<<MAX_DET / 256, 256, 0, stream>>>(x, flatidx, total, out);
}